// Round 1
// baseline (1182.678 us; speedup 1.0000x reference)
//
#include <hip/hip_runtime.h>

// KANConv2d fused kernel (fp32 baseline).
// out[b,o,h,w] = sum_{c,kh,kw} beta[o,c,kh,kw]*silu(v) +
//                sum_{s<7}     spline[o,c,kh,kw]*coeffs[s,o,c,kh,kw]*B_s(v)
//   with v = xp[b,c,h+kh-1,w+kw-1]  (zero-padded; features of v=0 are NOT zero)
//
// Per-pixel feature vector f[8] = {silu(v), B_0(v)..B_6(v)} where B_s are
// cardinal cubic B-splines on uniform knots -2.5..2.5 step 0.5.

#define BB 16
#define CC 64
#define HH 64
#define WW 64
#define OO 128
#define NF 8
#define WPAD 12   // padded inner stride of Wl: 12 floats = 48 B (16B-aligned, breaks 32-bank aliasing)

__global__ __launch_bounds__(256) void kan_fused(
    const float* __restrict__ x,
    const float* __restrict__ beta,
    const float* __restrict__ spl,
    const float* __restrict__ cf,
    float* __restrict__ out)
{
    // Features: [feature j][row kh][wp 0..65], wp stride 72 floats
    __shared__ float Fl[NF][3][72];
    // Combined weights: [o_local][tap][j], inner stride WPAD
    __shared__ float Wl[64][9][WPAD];

    const int blk   = blockIdx.x;
    const int otile = blk & 1;        // 2 o-tiles of 64
    const int bh    = blk >> 1;
    const int h     = bh & (HH - 1);
    const int b     = bh >> 6;

    const int tid = threadIdx.x;
    const int wt  = tid & 15;         // 16 w-tiles of 4
    const int ot  = tid >> 4;         // 16 o-slots of 4
    const int w0  = wt << 2;

    float acc[4][4];                  // [o_q][w_p]
    #pragma unroll
    for (int q = 0; q < 4; ++q)
        #pragma unroll
        for (int p = 0; p < 4; ++p) acc[q][p] = 0.f;

    // feature-staging decomposition of tid (198 = 3 rows x 66 pixels)
    const int fkh = tid / 66;
    const int fwp = tid - fkh * 66;

    for (int c = 0; c < CC; ++c) {
        __syncthreads();   // previous iteration's consumers done before overwrite

        // ---------- stage features ----------
        if (tid < 198) {
            const int hp = h + fkh - 1;
            const int wx = fwp - 1;
            float v = 0.f;
            if ((unsigned)hp < (unsigned)HH && (unsigned)wx < (unsigned)WW)
                v = x[((b * CC + c) * HH + hp) * WW + wx];

            // silu
            Fl[0][fkh][fwp] = v / (1.f + __expf(-v));

            // zero all 7 basis slots, then write the <=4 nonzero ones
            #pragma unroll
            for (int s = 0; s < 7; ++s) Fl[1 + s][fkh][fwp] = 0.f;

            const float t = 2.f * v + 5.f;
            if (t >= 0.f && t < 10.f) {
                const int   i  = (int)t;          // interval 0..9
                const float u  = t - (float)i;    // [0,1)
                const float um = 1.f - u;
                const float u2 = u * u, u3 = u2 * u;
                const float k0 = um * um * um * (1.f / 6.f);
                const float k1 = (3.f * u3 - 6.f * u2 + 4.f) * (1.f / 6.f);
                const float k2 = (-3.f * u3 + 3.f * u2 + 3.f * u + 1.f) * (1.f / 6.f);
                const float k3 = u3 * (1.f / 6.f);
                const float kv[4] = {k0, k1, k2, k3};
                const int s0 = i - 3;
                #pragma unroll
                for (int m = 0; m < 4; ++m) {
                    const int s = s0 + m;
                    if (s >= 0 && s < 7) Fl[1 + s][fkh][fwp] = kv[m];
                }
            }
        }

        // ---------- stage combined weights ----------
        {
            const int o_l = tid >> 2;                 // 0..63
            const int o_g = otile * 64 + o_l;
            const int wbase = (o_g * CC + c) * 9;
            #pragma unroll
            for (int pass = 0; pass < 2; ++pass) {
                const int j = pass * 4 + (tid & 3);   // 0..7
                if (j == 0) {
                    #pragma unroll
                    for (int tap = 0; tap < 9; ++tap)
                        Wl[o_l][tap][0] = beta[wbase + tap];
                } else {
                    const int s = j - 1;
                    const float* cfp = cf + ((s * OO + o_g) * CC + c) * 9;
                    #pragma unroll
                    for (int tap = 0; tap < 9; ++tap)
                        Wl[o_l][tap][j] = spl[wbase + tap] * cfp[tap];
                }
            }
        }

        __syncthreads();

        // ---------- accumulate ----------
        #pragma unroll
        for (int kh = 0; kh < 3; ++kh) {
            float fr[NF][6];
            #pragma unroll
            for (int j = 0; j < NF; ++j)
                #pragma unroll
                for (int r = 0; r < 6; ++r)
                    fr[j][r] = Fl[j][kh][w0 + r];

            #pragma unroll
            for (int kw = 0; kw < 3; ++kw) {
                const int tap = kh * 3 + kw;
                #pragma unroll
                for (int q = 0; q < 4; ++q) {
                    float wv[NF];
                    #pragma unroll
                    for (int j = 0; j < NF; ++j)
                        wv[j] = Wl[ot * 4 + q][tap][j];
                    #pragma unroll
                    for (int j = 0; j < NF; ++j)
                        #pragma unroll
                        for (int p = 0; p < 4; ++p)
                            acc[q][p] += wv[j] * fr[j][kw + p];
                }
            }
        }
    }

    // ---------- store ----------
    #pragma unroll
    for (int q = 0; q < 4; ++q) {
        const int o = otile * 64 + ot * 4 + q;
        float4 v4 = make_float4(acc[q][0], acc[q][1], acc[q][2], acc[q][3]);
        *(float4*)&out[((b * OO + o) * HH + h) * WW + w0] = v4;
    }
}

extern "C" void kernel_launch(void* const* d_in, const int* in_sizes, int n_in,
                              void* d_out, int out_size, void* d_ws, size_t ws_size,
                              hipStream_t stream) {
    const float* x    = (const float*)d_in[0];
    const float* beta = (const float*)d_in[1];
    const float* spl  = (const float*)d_in[2];
    const float* cf   = (const float*)d_in[3];
    float* out = (float*)d_out;

    dim3 grid(BB * HH * 2);   // (b,h) x 2 o-tiles
    dim3 block(256);
    kan_fused<<<grid, block, 0, stream>>>(x, beta, spl, cf, out);
}

// Round 2
// 143.602 us; speedup vs baseline: 8.2358x; 8.2358x over previous
//
#include <hip/hip_runtime.h>

// KANConv2d as implicit GEMM on matrix cores.
// out[b,o,h,w] = sum_{c,tap,j} Wc[o,c,tap,j] * f_j(xp[b,c,h+dh,w+dw])
//   f = {silu(v), B_0(v)..B_6(v)}, cardinal cubic B-splines, knots -2.5..2.5 step 0.5
// GEMM: D[o][pixel], K ordered (cb, tap, c_l, j):  k-chunk of 32 = 4 channels x 8 features.
// MFMA v_mfma_f32_32x32x16_bf16: A=W[o][k], B=F[k][pixel]; lane's 8 input elems are
// k-contiguous => A-frag = one 16B global load, B-frag = one ds_read_b128.

#define BB 16
#define CC 64
#define HH 64
#define WW 64
#define OO 128

typedef __bf16 bf16x8 __attribute__((ext_vector_type(8)));
typedef float f32x16 __attribute__((ext_vector_type(16)));

__device__ __forceinline__ unsigned bf16rne(float f) {
    unsigned u = __float_as_uint(f);
    return (u + 0x7FFFu + ((u >> 16) & 1u)) >> 16;   // round-to-nearest-even bf16
}

__device__ __forceinline__ bf16x8 as_bf16x8(uint4 v) {
    return __builtin_bit_cast(bf16x8, v);
}

// ---------------- weight prep: Wb[cb][tap][c_l][o][j] bf16, j contiguous ----------------
__global__ __launch_bounds__(256) void kan_wprep(
    const float* __restrict__ beta, const float* __restrict__ spl,
    const float* __restrict__ cf, uint4* __restrict__ wb)
{
    int t = blockIdx.x * 256 + threadIdx.x;      // 73728 = (o, c, tap)
    int tap = t % 9;
    int c   = (t / 9) & 63;
    int o   = t / 576;
    int base = (o * CC + c) * 9 + tap;
    float bv = beta[base];
    float sv = spl[base];
    float f[8];
    f[0] = bv;
    #pragma unroll
    for (int s = 0; s < 7; ++s)
        f[1 + s] = sv * cf[((s * OO + o) * CC + c) * 9 + tap];
    uint4 pk;
    pk.x = bf16rne(f[0]) | (bf16rne(f[1]) << 16);
    pk.y = bf16rne(f[2]) | (bf16rne(f[3]) << 16);
    pk.z = bf16rne(f[4]) | (bf16rne(f[5]) << 16);
    pk.w = bf16rne(f[6]) | (bf16rne(f[7]) << 16);
    int cb = c >> 2, cl = c & 3;
    wb[((cb * 9 + tap) * 4 + cl) * OO + o] = pk;
}

// ---------------- main fused conv ----------------
__global__ __launch_bounds__(256) void kan_mfma(
    const float* __restrict__ x, const uint4* __restrict__ wb,
    float* __restrict__ out)
{
    // feature tile: [c_l 0..3][row 0..3][wp 0..65] -> 8 bf16 (16B granule)
    __shared__ uint4 ft[4 * 4 * 66];

    const int tid  = threadIdx.x;
    const int blk  = blockIdx.x;
    const int h0   = (blk & 31) << 1;   // 2 output rows per block
    const int b    = blk >> 5;

    const int ww    = tid >> 6;         // wave 0..3
    const int lane  = tid & 63;
    const int lo    = lane & 31;
    const int hi    = lane >> 5;
    const int ohalf = ww & 1;           // which 64-o half
    const int hrow  = ww >> 1;          // which output row

    f32x16 acc[2][2];                   // [o-frag][w-frag]
    #pragma unroll
    for (int i = 0; i < 2; ++i)
        #pragma unroll
        for (int j = 0; j < 2; ++j)
            #pragma unroll
            for (int r = 0; r < 16; ++r) acc[i][j][r] = 0.f;

    // staging decomposition: 16 (c_l,row) combos x 16 wp lanes
    const int scl  = (tid >> 4) & 3;
    const int srow = tid >> 6;
    const int swp0 = tid & 15;

    for (int cb = 0; cb < 16; ++cb) {
        __syncthreads();
        // ---- stage features for channels cb*4 .. cb*4+3 ----
        #pragma unroll
        for (int it = 0; it < 5; ++it) {
            const int wp = swp0 + it * 16;
            if (it < 4 || swp0 < 2) {
                const int c  = cb * 4 + scl;
                const int hp = h0 - 1 + srow;
                const int wx = wp - 1;
                float v = 0.f;
                if ((unsigned)hp < 64u && (unsigned)wx < 64u)
                    v = x[((b * CC + c) * HH + hp) * WW + wx];

                const float silu = __fdividef(v, 1.f + __expf(-v));
                const float t  = 2.f * v + 5.f;
                const float fi = floorf(t);
                const float u  = t - fi;
                const float um = 1.f - u;
                const float u2 = u * u, u3 = u2 * u;
                const float k0 = um * um * um * (1.f / 6.f);
                const float k1 = (3.f * u3 - 6.f * u2 + 4.f) * (1.f / 6.f);
                const float k2 = (-3.f * u3 + 3.f * u2 + 3.f * u + 1.f) * (1.f / 6.f);
                const float k3 = u3 * (1.f / 6.f);
                const bool valid = (t >= 0.f) && (t < 10.f);
                const int  is0   = (int)fi - 3;     // first nonzero basis slot

                float fb[7];
                #pragma unroll
                for (int s = 0; s < 7; ++s) {
                    const int d = s - is0;
                    float kv = (d == 0) ? k0 : (d == 1) ? k1 : (d == 2) ? k2 : (d == 3) ? k3 : 0.f;
                    fb[s] = valid ? kv : 0.f;
                }
                uint4 pk;
                pk.x = bf16rne(silu)  | (bf16rne(fb[0]) << 16);
                pk.y = bf16rne(fb[1]) | (bf16rne(fb[2]) << 16);
                pk.z = bf16rne(fb[3]) | (bf16rne(fb[4]) << 16);
                pk.w = bf16rne(fb[5]) | (bf16rne(fb[6]) << 16);
                ft[(scl * 4 + srow) * 66 + wp] = pk;
            }
        }
        __syncthreads();

        // ---- 9 taps: K-chunk of 32 each (4 channels x 8 features) ----
        #pragma unroll
        for (int tap = 0; tap < 9; ++tap) {
            const int dh = tap / 3;     // 0..2 (input row = hrow + dh in tile coords)
            const int dw = tap % 3;     // 0..2 (wp = w + dw)

            bf16x8 a[2][2], fB[2][2];
            #pragma unroll
            for (int kh = 0; kh < 2; ++kh) {
                const int cl = kh * 2 + hi;
                const int wrow = ((cb * 9 + tap) * 4 + cl) * OO;
                #pragma unroll
                for (int oi = 0; oi < 2; ++oi)
                    a[oi][kh] = as_bf16x8(wb[wrow + ohalf * 64 + oi * 32 + lo]);
                const int ldsrow = (cl * 4 + (hrow + dh)) * 66;
                #pragma unroll
                for (int wi = 0; wi < 2; ++wi)
                    fB[wi][kh] = as_bf16x8(ft[ldsrow + wi * 32 + lo + dw]);
            }
            #pragma unroll
            for (int oi = 0; oi < 2; ++oi)
                #pragma unroll
                for (int wi = 0; wi < 2; ++wi)
                    #pragma unroll
                    for (int kh = 0; kh < 2; ++kh)
                        acc[oi][wi] = __builtin_amdgcn_mfma_f32_32x32x16_bf16(
                            a[oi][kh], fB[wi][kh], acc[oi][wi], 0, 0, 0);
        }
    }

    // ---- store: D row = o, col = pixel(w) -> w-coalesced dword stores ----
    const int h = h0 + hrow;
    #pragma unroll
    for (int oi = 0; oi < 2; ++oi) {
        #pragma unroll
        for (int wi = 0; wi < 2; ++wi) {
            const int wc = wi * 32 + lo;
            #pragma unroll
            for (int r = 0; r < 16; ++r) {
                const int o = ohalf * 64 + oi * 32 + (r & 3) + ((r >> 2) << 3) + (hi << 2);
                out[((b * OO + o) * HH + h) * WW + wc] = acc[oi][wi][r];
            }
        }
    }
}

extern "C" void kernel_launch(void* const* d_in, const int* in_sizes, int n_in,
                              void* d_out, int out_size, void* d_ws, size_t ws_size,
                              hipStream_t stream) {
    const float* x    = (const float*)d_in[0];
    const float* beta = (const float*)d_in[1];
    const float* spl  = (const float*)d_in[2];
    const float* cf   = (const float*)d_in[3];
    float* out = (float*)d_out;
    uint4* wb  = (uint4*)d_ws;          // 73728 * 16 B = 1.18 MB

    kan_wprep<<<288, 256, 0, stream>>>(beta, spl, cf, wb);
    kan_mfma<<<BB * (HH / 2), 256, 0, stream>>>(x, wb, out);
}

// Round 3
// 109.158 us; speedup vs baseline: 10.8346x; 1.3155x over previous
//
#include <hip/hip_runtime.h>

// KANConv2d as implicit GEMM on matrix cores, round 3.
// GEMM: D[o][pixel] = sum_k W[o][k] * F[k][pixel], K = (cb, tap, c_l, j) = 4608.
// f = {silu(v), B_0..B_6(v)}, cardinal cubic B-splines, t = 2v+5, support t in [s, s+4).
// Round-3 structure: double-buffered feature LDS (1 barrier/cb), A-frag tap-prefetch,
// 128-bit-shift basis scatter (replaces compare/select chain).

#define BB 16
#define CC 64
#define HH 64
#define WW 64
#define OO 128

typedef __bf16 bf16x8 __attribute__((ext_vector_type(8)));
typedef float f32x16 __attribute__((ext_vector_type(16)));

__device__ __forceinline__ bf16x8 as_bf16x8(uint4 v) { return __builtin_bit_cast(bf16x8, v); }
__device__ __forceinline__ unsigned bfb(float f) {
    return (unsigned)__builtin_bit_cast(unsigned short, (__bf16)f);
}

// ---------------- weight prep: Wb[cb][tap][c_l][o][j] bf16, j contiguous ----------------
__global__ __launch_bounds__(256) void kan_wprep(
    const float* __restrict__ beta, const float* __restrict__ spl,
    const float* __restrict__ cf, uint4* __restrict__ wb)
{
    int t = blockIdx.x * 256 + threadIdx.x;      // 73728 = (o, c, tap)
    int tap = t % 9;
    int c   = (t / 9) & 63;
    int o   = t / 576;
    int base = (o * CC + c) * 9 + tap;
    float bv = beta[base];
    float sv = spl[base];
    float f[8];
    f[0] = bv;
    #pragma unroll
    for (int s = 0; s < 7; ++s)
        f[1 + s] = sv * cf[((s * OO + o) * CC + c) * 9 + tap];
    uint4 pk;
    pk.x = bfb(f[0]) | (bfb(f[1]) << 16);
    pk.y = bfb(f[2]) | (bfb(f[3]) << 16);
    pk.z = bfb(f[4]) | (bfb(f[5]) << 16);
    pk.w = bfb(f[6]) | (bfb(f[7]) << 16);
    int cb = c >> 2, cl = c & 3;
    wb[((cb * 9 + tap) * 4 + cl) * OO + o] = pk;
}

// ---------------- main fused conv ----------------
__global__ __launch_bounds__(256) void kan_mfma(
    const float* __restrict__ x, const uint4* __restrict__ wb,
    float* __restrict__ out)
{
    // double-buffered feature tile: [buf][c_l 0..3][row 0..3][wp 0..65], 16B granules
    __shared__ uint4 ft[2][4 * 4 * 66];

    const int tid  = threadIdx.x;
    const int blk  = blockIdx.x;
    const int h0   = (blk & 31) << 1;   // 2 output rows per block
    const int b    = blk >> 5;

    const int ww    = tid >> 6;         // wave 0..3
    const int lane  = tid & 63;
    const int lo    = lane & 31;
    const int hi    = lane >> 5;
    const int ohalf = ww & 1;           // which 64-o half
    const int hrow  = ww >> 1;          // which output row

    // staging decomposition: (c_l, input row, 16 wp lanes)
    const int scl  = (tid >> 4) & 3;
    const int srow = tid >> 6;
    const int swp0 = tid & 15;
    const int hp   = h0 - 1 + srow;
    const bool hok = (unsigned)hp < 64u;

    f32x16 acc[2][2] = {};              // [o-frag][w-frag]

    float xn[5];

    // ---- load x values for one channel-block into registers ----
    #define LOADX(cbi) do {                                                   \
        const int c_ = (cbi) * 4 + scl;                                       \
        const float* xr = x + ((b * CC + c_) * HH + hp) * WW;                 \
        _Pragma("unroll")                                                     \
        for (int it = 0; it < 5; ++it) {                                      \
            const int wx = swp0 + it * 16 - 1;                                \
            const bool act = (it < 4 || swp0 < 2) && hok &&                   \
                             ((unsigned)wx < 64u);                            \
            xn[it] = act ? xr[wx] : 0.f;                                      \
        }                                                                     \
    } while (0)

    // ---- compute features from xn, write to ft[bufi] ----
    #define STAGE(bufi) do {                                                  \
        _Pragma("unroll")                                                     \
        for (int it = 0; it < 5; ++it) {                                      \
            if (it < 4 || swp0 < 2) {                                         \
                const int wp = swp0 + it * 16;                                \
                const float v = xn[it];                                       \
                const float silu = __fdividef(v, 1.f + __expf(-v));           \
                const float t  = fmaf(2.f, v, 5.f);                           \
                const float fi = floorf(t);                                   \
                const float u  = t - fi;                                      \
                const float um = 1.f - u;                                     \
                const float u2 = u * u, u3 = u2 * u;                          \
                const float k0 = um * um * um * (1.f / 6.f);                  \
                const float k1 = fmaf(0.5f, u3, (2.f / 3.f) - u2);            \
                const float k2 = fmaf(-0.5f, u3,                              \
                                   fmaf(0.5f, u2, fmaf(0.5f, u, 1.f / 6.f))); \
                const float k3 = u3 * (1.f / 6.f);                            \
                const bool valid = (t >= 0.f) && (t < 10.f);                  \
                unsigned long long K =                                        \
                    (unsigned long long)bfb(k0)        |                      \
                    ((unsigned long long)bfb(k1) << 16) |                     \
                    ((unsigned long long)bfb(k2) << 32) |                     \
                    ((unsigned long long)bfb(k3) << 48);                      \
                if (!valid) K = 0ull;                                         \
                const int ic = min(max((int)fi, -2), 9);                      \
                const int sh = 16 * ic - 32;          /* [-64, 112] */        \
                unsigned __int128 P = (sh >= 0)                               \
                    ? ((unsigned __int128)K << sh)                            \
                    : ((unsigned __int128)K >> (-sh));                        \
                uint4 pk = __builtin_bit_cast(uint4, P);                      \
                pk.x = (pk.x & 0xFFFF0000u) | bfb(silu);                      \
                ft[bufi][(scl * 4 + srow) * 66 + wp] = pk;                    \
            }                                                                 \
        }                                                                     \
    } while (0)

    // ---- A-fragment load for one (cb, tap): [kh][oi] ----
    uint4 A0[2][2], A1[2][2];
    #define LOADA(dst, cbi, tapi) do {                                        \
        _Pragma("unroll")                                                     \
        for (int kh = 0; kh < 2; ++kh) {                                      \
            const int cl = kh * 2 + hi;                                       \
            const uint4* wr = wb + (((cbi) * 9 + (tapi)) * 4 + cl) * OO       \
                              + ohalf * 64 + lo;                              \
            dst[kh][0] = wr[0];                                               \
            dst[kh][1] = wr[32];                                              \
        }                                                                     \
    } while (0)

    // prologue: stage cb=0
    LOADX(0);
    STAGE(0);
    __syncthreads();

    #pragma unroll 1
    for (int cb = 0; cb < 16; ++cb) {
        const int buf = cb & 1;
        if (cb < 15) LOADX(cb + 1);     // issue next x loads early
        LOADA(A0, cb, 0);
        const uint4* ftb = ft[buf];

        #pragma unroll
        for (int tap = 0; tap < 9; ++tap) {
            const int dh = tap / 3;
            const int dw = tap % 3;
            if (tap < 8) {
                if (tap & 1) LOADA(A0, cb, tap + 1);
                else         LOADA(A1, cb, tap + 1);
            }
            bf16x8 Bf[2][2];            // [wi][kh]
            #pragma unroll
            for (int kh = 0; kh < 2; ++kh) {
                const int cl = kh * 2 + hi;
                const uint4* fr = ftb + (cl * 4 + hrow + dh) * 66 + dw + lo;
                Bf[0][kh] = as_bf16x8(fr[0]);
                Bf[1][kh] = as_bf16x8(fr[32]);
            }
            uint4 (&A)[2][2] = (tap & 1) ? A1 : A0;
            #pragma unroll
            for (int oi = 0; oi < 2; ++oi)
                #pragma unroll
                for (int wi = 0; wi < 2; ++wi)
                    #pragma unroll
                    for (int kh = 0; kh < 2; ++kh)
                        acc[oi][wi] = __builtin_amdgcn_mfma_f32_32x32x16_bf16(
                            as_bf16x8(A[kh][oi]), Bf[wi][kh], acc[oi][wi], 0, 0, 0);
        }

        if (cb < 15) STAGE(buf ^ 1);    // feature VALU overlaps with above in sched window
        __syncthreads();
    }

    // ---- store: D row = o, col = pixel(w) -> w-coalesced dword stores ----
    const int h = h0 + hrow;
    #pragma unroll
    for (int oi = 0; oi < 2; ++oi) {
        #pragma unroll
        for (int wi = 0; wi < 2; ++wi) {
            const int wc = wi * 32 + lo;
            #pragma unroll
            for (int r = 0; r < 16; ++r) {
                const int o = ohalf * 64 + oi * 32 + (r & 3) + ((r >> 2) << 3) + (hi << 2);
                out[((b * OO + o) * HH + h) * WW + wc] = acc[oi][wi][r];
            }
        }
    }
}

extern "C" void kernel_launch(void* const* d_in, const int* in_sizes, int n_in,
                              void* d_out, int out_size, void* d_ws, size_t ws_size,
                              hipStream_t stream) {
    const float* x    = (const float*)d_in[0];
    const float* beta = (const float*)d_in[1];
    const float* spl  = (const float*)d_in[2];
    const float* cf   = (const float*)d_in[3];
    float* out = (float*)d_out;
    uint4* wb  = (uint4*)d_ws;          // 73728 * 16 B = 1.18 MB

    kan_wprep<<<288, 256, 0, stream>>>(beta, spl, cf, wb);
    kan_mfma<<<BB * (HH / 2), 256, 0, stream>>>(x, wb, out);
}

// Round 4
// 102.653 us; speedup vs baseline: 11.5211x; 1.0634x over previous
//
#include <hip/hip_runtime.h>

// KANConv2d as implicit GEMM on matrix cores, round 4.
// GEMM: D[o][pixel] = sum_k W[o][k] * F[k][pixel], K = (cb, tap, c_l, j) = 4608.
// f = {silu(v), B_0..B_6(v)}, cardinal cubic B-splines, t = 2v+5.
// R4: 512-thread blocks (8 waves, 64o x 32w x 1h per wave), same 512-block grid
//     -> 16 waves/CU (was 8). Staging total unchanged; acc regs halve.

#define BB 16
#define CC 64
#define HH 64
#define WW 64
#define OO 128

typedef __bf16 bf16x8 __attribute__((ext_vector_type(8)));
typedef float f32x16 __attribute__((ext_vector_type(16)));

__device__ __forceinline__ bf16x8 as_bf16x8(uint4 v) { return __builtin_bit_cast(bf16x8, v); }
__device__ __forceinline__ unsigned bfb(float f) {
    return (unsigned)__builtin_bit_cast(unsigned short, (__bf16)f);
}

// ---------------- weight prep: Wb[cb][tap][c_l][o][j] bf16, j contiguous ----------------
__global__ __launch_bounds__(256) void kan_wprep(
    const float* __restrict__ beta, const float* __restrict__ spl,
    const float* __restrict__ cf, uint4* __restrict__ wb)
{
    int t = blockIdx.x * 256 + threadIdx.x;      // 73728 = (o, c, tap)
    int tap = t % 9;
    int c   = (t / 9) & 63;
    int o   = t / 576;
    int base = (o * CC + c) * 9 + tap;
    float bv = beta[base];
    float sv = spl[base];
    float f[8];
    f[0] = bv;
    #pragma unroll
    for (int s = 0; s < 7; ++s)
        f[1 + s] = sv * cf[((s * OO + o) * CC + c) * 9 + tap];
    uint4 pk;
    pk.x = bfb(f[0]) | (bfb(f[1]) << 16);
    pk.y = bfb(f[2]) | (bfb(f[3]) << 16);
    pk.z = bfb(f[4]) | (bfb(f[5]) << 16);
    pk.w = bfb(f[6]) | (bfb(f[7]) << 16);
    int cb = c >> 2, cl = c & 3;
    wb[((cb * 9 + tap) * 4 + cl) * OO + o] = pk;
}

// ---------------- main fused conv ----------------
__global__ __launch_bounds__(512, 4) void kan_mfma(
    const float* __restrict__ x, const uint4* __restrict__ wb,
    float* __restrict__ out)
{
    // double-buffered feature tile: [buf][c_l 0..3][row 0..3][wp 0..65], 16B granules
    __shared__ uint4 ft[2][4 * 4 * 66];

    const int tid  = threadIdx.x;
    const int blk  = blockIdx.x;
    const int h0   = (blk & 31) << 1;   // 2 output rows per block
    const int b    = blk >> 5;

    const int ww    = tid >> 6;         // wave 0..7
    const int lane  = tid & 63;
    const int lo    = lane & 31;
    const int hi    = lane >> 5;
    const int ohalf = ww & 1;           // which 64-o half
    const int hrow  = (ww >> 1) & 1;    // which output row
    const int wtile = ww >> 2;          // which 32-w tile

    // staging decomposition: (c_l, input row, 32 wp lanes)
    const int scl  = (tid >> 5) & 3;
    const int srow = tid >> 7;
    const int swp0 = tid & 31;
    const int hp   = h0 - 1 + srow;
    const bool hok = (unsigned)hp < 64u;

    f32x16 acc[2] = {};                 // [o-frag]

    float xn[3];

    // ---- load x values for one channel-block into registers ----
    #define LOADX(cbi) do {                                                   \
        const int c_ = (cbi) * 4 + scl;                                       \
        const float* xr = x + ((b * CC + c_) * HH + hp) * WW;                 \
        _Pragma("unroll")                                                     \
        for (int it = 0; it < 3; ++it) {                                      \
            const int wx = swp0 + it * 32 - 1;                                \
            const bool act = (it < 2 || swp0 < 2) && hok &&                   \
                             ((unsigned)wx < 64u);                            \
            xn[it] = act ? xr[wx] : 0.f;                                      \
        }                                                                     \
    } while (0)

    // ---- compute features from xn, write to ft[bufi] ----
    #define STAGE(bufi) do {                                                  \
        _Pragma("unroll")                                                     \
        for (int it = 0; it < 3; ++it) {                                      \
            if (it < 2 || swp0 < 2) {                                         \
                const int wp = swp0 + it * 32;                                \
                const float v = xn[it];                                       \
                const float silu = __fdividef(v, 1.f + __expf(-v));           \
                const float t  = fmaf(2.f, v, 5.f);                           \
                const float fi = floorf(t);                                   \
                const float u  = t - fi;                                      \
                const float um = 1.f - u;                                     \
                const float u2 = u * u, u3 = u2 * u;                          \
                const float k0 = um * um * um * (1.f / 6.f);                  \
                const float k1 = fmaf(0.5f, u3, (2.f / 3.f) - u2);            \
                const float k2 = fmaf(-0.5f, u3,                              \
                                   fmaf(0.5f, u2, fmaf(0.5f, u, 1.f / 6.f))); \
                const float k3 = u3 * (1.f / 6.f);                            \
                const bool valid = (t >= 0.f) && (t < 10.f);                  \
                unsigned long long K =                                        \
                    (unsigned long long)bfb(k0)        |                      \
                    ((unsigned long long)bfb(k1) << 16) |                     \
                    ((unsigned long long)bfb(k2) << 32) |                     \
                    ((unsigned long long)bfb(k3) << 48);                      \
                if (!valid) K = 0ull;                                         \
                const int ic = min(max((int)fi, -2), 9);                      \
                const int sh = 16 * ic - 32;          /* [-64, 112] */        \
                unsigned __int128 P = (sh >= 0)                               \
                    ? ((unsigned __int128)K << sh)                            \
                    : ((unsigned __int128)K >> (-sh));                        \
                uint4 pk = __builtin_bit_cast(uint4, P);                      \
                pk.x = (pk.x & 0xFFFF0000u) | bfb(silu);                      \
                ft[bufi][(scl * 4 + srow) * 66 + wp] = pk;                    \
            }                                                                 \
        }                                                                     \
    } while (0)

    // ---- A-fragment load for one (cb, tap): [kh][oi] ----
    uint4 A0[2][2], A1[2][2];
    #define LOADA(dst, cbi, tapi) do {                                        \
        _Pragma("unroll")                                                     \
        for (int kh = 0; kh < 2; ++kh) {                                      \
            const int cl = kh * 2 + hi;                                       \
            const uint4* wr = wb + (((cbi) * 9 + (tapi)) * 4 + cl) * OO       \
                              + ohalf * 64 + lo;                              \
            dst[kh][0] = wr[0];                                               \
            dst[kh][1] = wr[32];                                              \
        }                                                                     \
    } while (0)

    // prologue: stage cb=0
    LOADX(0);
    STAGE(0);
    __syncthreads();

    #pragma unroll 1
    for (int cb = 0; cb < 16; ++cb) {
        const int buf = cb & 1;
        if (cb < 15) LOADX(cb + 1);     // issue next x loads early
        LOADA(A0, cb, 0);
        const uint4* ftb = ft[buf];

        #pragma unroll
        for (int tap = 0; tap < 9; ++tap) {
            const int dh = tap / 3;
            const int dw = tap % 3;
            if (tap < 8) {
                if (tap & 1) LOADA(A0, cb, tap + 1);
                else         LOADA(A1, cb, tap + 1);
            }
            bf16x8 Bf[2];               // [kh]
            #pragma unroll
            for (int kh = 0; kh < 2; ++kh) {
                const int cl = kh * 2 + hi;
                const uint4* fr = ftb + (cl * 4 + hrow + dh) * 66
                                  + wtile * 32 + dw + lo;
                Bf[kh] = as_bf16x8(fr[0]);
            }
            uint4 (&A)[2][2] = (tap & 1) ? A1 : A0;
            #pragma unroll
            for (int oi = 0; oi < 2; ++oi)
                #pragma unroll
                for (int kh = 0; kh < 2; ++kh)
                    acc[oi] = __builtin_amdgcn_mfma_f32_32x32x16_bf16(
                        as_bf16x8(A[kh][oi]), Bf[kh], acc[oi], 0, 0, 0);
        }

        if (cb < 15) STAGE(buf ^ 1);    // feature VALU overlaps with MFMAs above
        __syncthreads();
    }

    // ---- store: D row = o, col = pixel(w) -> w-coalesced dword stores ----
    const int h  = h0 + hrow;
    const int wc = wtile * 32 + lo;
    #pragma unroll
    for (int oi = 0; oi < 2; ++oi) {
        #pragma unroll
        for (int r = 0; r < 16; ++r) {
            const int o = ohalf * 64 + oi * 32 + (r & 3) + ((r >> 2) << 3) + (hi << 2);
            out[((b * OO + o) * HH + h) * WW + wc] = acc[oi][r];
        }
    }
}

extern "C" void kernel_launch(void* const* d_in, const int* in_sizes, int n_in,
                              void* d_out, int out_size, void* d_ws, size_t ws_size,
                              hipStream_t stream) {
    const float* x    = (const float*)d_in[0];
    const float* beta = (const float*)d_in[1];
    const float* spl  = (const float*)d_in[2];
    const float* cf   = (const float*)d_in[3];
    float* out = (float*)d_out;
    uint4* wb  = (uint4*)d_ws;          // 73728 * 16 B = 1.18 MB

    kan_wprep<<<288, 256, 0, stream>>>(beta, spl, cf, wb);
    kan_mfma<<<BB * (HH / 2), 512, 0, stream>>>(x, wb, out);
}